// Round 3
// baseline (1469.016 us; speedup 1.0000x reference)
//
#include <hip/hip_runtime.h>
#include <stdint.h>

// Problem: B=32, N=512, E=1024, H=8, L=3, FF=2048, KD=128, DK=16
// M = B*N = 16384 rows. Input/output transport dtype (f32 vs bf16) is
// DETECTED ON DEVICE (flag in ws): compute is bf16 MFMA + f32 master h.

typedef __attribute__((ext_vector_type(8))) short short8;
typedef __attribute__((ext_vector_type(4))) float floatx4;

#define NORM_ 0.08838834764831845f   // 1/sqrt(128)

__device__ __forceinline__ float bf2f(unsigned short u) {
    union { unsigned int i; float f; } x; x.i = ((unsigned int)u) << 16; return x.f;
}
__device__ __forceinline__ float bitsf(unsigned int i) {
    union { unsigned int i; float f; } x; x.i = i; return x.f;
}
__device__ __forceinline__ unsigned short f2bf(float f) {  // RNE
    union { float f; unsigned int i; } x; x.f = f;
    unsigned int u = x.i;
    u += 0x7FFFu + ((u >> 16) & 1u);
    return (unsigned short)(u >> 16);
}

// ---- transport dtype detection -------------------------------------------
// bf16-pair words: low 16 bits are a sane bf16 (exp field in [90,145]).
// f32 words: low 16 bits are random mantissa bits (~21% in range).
__global__ __launch_bounds__(256) void detect_dtype(const unsigned int* __restrict__ x,
                                                    int* __restrict__ flag)
{
    __shared__ int good, bad;
    if (threadIdx.x == 0) { good = 0; bad = 0; }
    __syncthreads();
    int g = 0, b = 0;
    for (int i = threadIdx.x; i < 4096; i += 256) {
        unsigned int lo = x[i] & 0xFFFFu;
        if (lo != 0u) {
            unsigned int e = (lo >> 7) & 0xFFu;
            if (e >= 90u && e <= 145u) ++g; else ++b;
        }
    }
    atomicAdd(&good, g); atomicAdd(&bad, b);
    __syncthreads();
    if (threadIdx.x == 0) *flag = (bad > good) ? 1 : 0;   // 1 = f32 transport
}

// convert one tensor (n elements, n % 8 == 0) to bf16 canonical
__global__ __launch_bounds__(256) void conv_to_bf16(const void* __restrict__ src,
                                                    unsigned short* __restrict__ dst,
                                                    int n, const int* __restrict__ flag)
{
    const int i = (blockIdx.x * 256 + threadIdx.x) * 8;
    if (i >= n) return;
    if (*flag) {
        const float* s = (const float*)src + i;
        floatx4 a = *(const floatx4*)s;
        floatx4 b = *(const floatx4*)(s + 4);
        short8 o;
        o[0] = (short)f2bf(a[0]); o[1] = (short)f2bf(a[1]);
        o[2] = (short)f2bf(a[2]); o[3] = (short)f2bf(a[3]);
        o[4] = (short)f2bf(b[0]); o[5] = (short)f2bf(b[1]);
        o[6] = (short)f2bf(b[2]); o[7] = (short)f2bf(b[3]);
        *(short8*)(dst + i) = o;
    } else {
        *(short8*)(dst + i) = *(const short8*)((const unsigned short*)src + i);
    }
}

__global__ __launch_bounds__(256) void init_h(const void* __restrict__ x,
                                              float* __restrict__ hf,
                                              unsigned short* __restrict__ hb,
                                              const int* __restrict__ flag)
{
    const size_t i = ((size_t)blockIdx.x * 256 + threadIdx.x) * 8;
    if (*flag) {
        const float* s = (const float*)x + i;
        floatx4 a = *(const floatx4*)s;
        floatx4 b = *(const floatx4*)(s + 4);
        short8 o;
        o[0] = (short)f2bf(a[0]); o[1] = (short)f2bf(a[1]);
        o[2] = (short)f2bf(a[2]); o[3] = (short)f2bf(a[3]);
        o[4] = (short)f2bf(b[0]); o[5] = (short)f2bf(b[1]);
        o[6] = (short)f2bf(b[2]); o[7] = (short)f2bf(b[3]);
        *(short8*)(hb + i) = o;
        *(floatx4*)(hf + i) = a;
        *(floatx4*)(hf + i + 4) = b;
    } else {
        short8 v = *(const short8*)((const unsigned short*)x + i);
        *(short8*)(hb + i) = v;
        #pragma unroll
        for (int e = 0; e < 8; ++e) hf[i + e] = bf2f((unsigned short)v[e]);
    }
}

// Detect mask transport (int32 / byte-bool / bf16 / f32) and expand to f32 0/1.
__global__ __launch_bounds__(256) void mask_expand(const unsigned int* __restrict__ mraw,
                                                   float* __restrict__ maskf)
{
    __shared__ unsigned int r[4];
    if (threadIdx.x < 4) r[threadIdx.x] = 0;
    __syncthreads();
    unsigned int gt1 = 0, badb = 0, badh = 0, lo3f = 0;
    for (int i = threadIdx.x; i < 4096; i += 256) {
        unsigned int w = mraw[i];
        if (w > 1u) gt1 = 1;
        if (w & 0xFEFEFEFEu) badb = 1;
        unsigned int lo = w & 0xFFFFu, hi = w >> 16;
        if ((lo != 0u && lo != 0x3F80u) || (hi != 0u && hi != 0x3F80u)) badh = 1;
        if (lo == 0x3F80u) lo3f = 1;
    }
    if (gt1) atomicOr(&r[0], 1u);
    if (badb) atomicOr(&r[1], 1u);
    if (badh) atomicOr(&r[2], 1u);
    if (lo3f) atomicOr(&r[3], 1u);
    __syncthreads();
    int cls;
    if (!r[0]) cls = 0;                 // words all 0/1 -> int32
    else if (!r[1]) cls = 1;            // bytes all 0/1 -> byte bool
    else if (!r[2]) cls = r[3] ? 2 : 3; // halves {0,0x3F80}: bf16 if low-half hits else f32
    else cls = 0;

    const int gid = blockIdx.x * 256 + threadIdx.x;  // 16384 elements
    bool m;
    if (cls == 0)      m = ((const int*)mraw)[gid] != 0;
    else if (cls == 1) m = ((const unsigned char*)mraw)[gid] != 0;
    else if (cls == 2) m = ((const unsigned short*)mraw)[gid] != 0;
    else               m = mraw[gid] != 0u;
    maskf[gid] = m ? 1.0f : 0.0f;
}

enum { EPI_NONE = 0, EPI_BIAS_RELU = 1, EPI_BIAS_RES = 2 };

// C[m,n] = sum_k A[m,k] * B[n,k]  (B stored N x K row-major).
// 128x128 tile, BK=32, 4 waves 2x2, wave does 64x64 = 4x4 MFMA tiles.
// Register-staged LDS with next-tile register prefetch.
template<int EPI>
__global__ __launch_bounds__(256) void gemm_bt(
    const unsigned short* __restrict__ A,
    const unsigned short* __restrict__ Bq,
    const unsigned short* __restrict__ Bk,
    const unsigned short* __restrict__ Bv,
    unsigned short* __restrict__ Cq,
    unsigned short* __restrict__ Ck,
    unsigned short* __restrict__ Cv,
    const unsigned short* __restrict__ bias,
    float* __restrict__ hf,
    unsigned short* __restrict__ hb,
    int N, int K)
{
    __shared__ __align__(16) unsigned short As[128 * 32];
    __shared__ __align__(16) unsigned short Bs[128 * 32];

    const int t = threadIdx.x;
    const int lane = t & 63;
    const int wave = t >> 6;
    const int bm = blockIdx.x;
    const int bn = blockIdx.y;
    const int bz = blockIdx.z;

    const unsigned short* Bmat = (bz == 0) ? Bq : ((bz == 1) ? Bk : Bv);
    unsigned short* C = (bz == 0) ? Cq : ((bz == 1) ? Ck : Cv);

    const int wm = (wave >> 1) * 64;
    const int wn = (wave & 1) * 64;

    const int srow = t >> 2;          // 0..63
    const int scol = (t & 3) * 8;     // 0,8,16,24 elements
    const unsigned short* Ag = A + (size_t)(bm * 128 + srow) * K + scol;
    const unsigned short* Bg = Bmat + (size_t)(bn * 128 + srow) * K + scol;
    unsigned short* As0 = &As[srow * 32 + scol];
    unsigned short* As1 = &As[(srow + 64) * 32 + scol];
    unsigned short* Bs0 = &Bs[srow * 32 + scol];
    unsigned short* Bs1 = &Bs[(srow + 64) * 32 + scol];
    const size_t rstep = (size_t)64 * K;

    const int fl = lane & 15;
    const int fk = (lane >> 4) * 8;
    int aoff[4], boff[4];
    #pragma unroll
    for (int i = 0; i < 4; ++i) {
        aoff[i] = (wm + i * 16 + fl) * 32 + fk;
        boff[i] = (wn + i * 16 + fl) * 32 + fk;
    }

    floatx4 acc[4][4];
    #pragma unroll
    for (int i = 0; i < 4; ++i)
        #pragma unroll
        for (int j = 0; j < 4; ++j) {
            acc[i][j][0] = 0.f; acc[i][j][1] = 0.f;
            acc[i][j][2] = 0.f; acc[i][j][3] = 0.f;
        }

    short8 ra0 = *(const short8*)(Ag);
    short8 ra1 = *(const short8*)(Ag + rstep);
    short8 rb0 = *(const short8*)(Bg);
    short8 rb1 = *(const short8*)(Bg + rstep);

    for (int k0 = 0; k0 < K; k0 += 32) {
        __syncthreads();
        *(short8*)As0 = ra0; *(short8*)As1 = ra1;
        *(short8*)Bs0 = rb0; *(short8*)Bs1 = rb1;
        __syncthreads();

        if (k0 + 32 < K) {
            ra0 = *(const short8*)(Ag + k0 + 32);
            ra1 = *(const short8*)(Ag + k0 + 32 + rstep);
            rb0 = *(const short8*)(Bg + k0 + 32);
            rb1 = *(const short8*)(Bg + k0 + 32 + rstep);
        }

        short8 af[4], bfr[4];
        #pragma unroll
        for (int i = 0; i < 4; ++i) af[i] = *(const short8*)&As[aoff[i]];
        #pragma unroll
        for (int j = 0; j < 4; ++j) bfr[j] = *(const short8*)&Bs[boff[j]];
        #pragma unroll
        for (int i = 0; i < 4; ++i)
            #pragma unroll
            for (int j = 0; j < 4; ++j)
                acc[i][j] = __builtin_amdgcn_mfma_f32_16x16x32_bf16(af[i], bfr[j], acc[i][j], 0, 0, 0);
    }

    // C/D: col = lane&15, row = (lane>>4)*4 + r
    const int r0 = (lane >> 4) * 4;
    #pragma unroll
    for (int j = 0; j < 4; ++j) {
        const int gcol = bn * 128 + wn + j * 16 + fl;
        float bval = 0.f;
        if (EPI != EPI_NONE) bval = bf2f(bias[gcol]);
        #pragma unroll
        for (int i = 0; i < 4; ++i) {
            const int growb = bm * 128 + wm + i * 16 + r0;
            #pragma unroll
            for (int r = 0; r < 4; ++r) {
                const size_t idx = (size_t)(growb + r) * N + gcol;
                float v = acc[i][j][r];
                if (EPI == EPI_NONE) {
                    C[idx] = f2bf(v);
                } else if (EPI == EPI_BIAS_RELU) {
                    v += bval;
                    v = v > 0.f ? v : 0.f;
                    C[idx] = f2bf(v);
                } else {
                    float nh = hf[idx] + v + bval;
                    hf[idx] = nh;
                    hb[idx] = f2bf(nh);
                }
            }
        }
    }
}

// One block per (h2,b2) pair; chunk p is contiguous 512x16 of Q/K/V.
// Max-rescaled online softmax: every exp arg <= 0.
__global__ __launch_bounds__(256) void attn_kernel(
    const unsigned short* __restrict__ Q,
    const unsigned short* __restrict__ Kx,
    const unsigned short* __restrict__ Vx,
    const float* __restrict__ maskf,
    unsigned short* __restrict__ Out)
{
    __shared__ __align__(16) float Ks[512 * 16];
    __shared__ __align__(16) unsigned short Vs[512 * 16];
    __shared__ float Ms[512];

    const int t = threadIdx.x;
    const int p = blockIdx.x;
    const int b2 = p & 31;
    const int h2 = p >> 5;

    const unsigned short* Kg = Kx + (size_t)p * 8192;
    const unsigned short* Vg = Vx + (size_t)p * 8192;
    #pragma unroll
    for (int it = 0; it < 4; ++it) {
        int i = it * 2048 + t * 8;
        short8 kv = *(const short8*)&Kg[i];
        #pragma unroll
        for (int e = 0; e < 8; ++e) Ks[i + e] = bf2f((unsigned short)kv[e]);
        *(short8*)&Vs[i] = *(const short8*)&Vg[i];
    }
    for (int i = t; i < 512; i += 256) Ms[i] = maskf[b2 * 512 + i];
    __syncthreads();

    float q0[16], q1[16];
    const unsigned short* qp = Q + (size_t)p * 8192 + t * 16;
    {
        short8 a = *(const short8*)qp;
        short8 b = *(const short8*)(qp + 8);
        short8 c = *(const short8*)(qp + 4096);
        short8 d = *(const short8*)(qp + 4096 + 8);
        #pragma unroll
        for (int e = 0; e < 8; ++e) {
            q0[e] = bf2f((unsigned short)a[e]); q0[8 + e] = bf2f((unsigned short)b[e]);
            q1[e] = bf2f((unsigned short)c[e]); q1[8 + e] = bf2f((unsigned short)d[e]);
        }
    }

    float o0[16], o1[16];
    #pragma unroll
    for (int d = 0; d < 16; ++d) { o0[d] = 0.f; o1[d] = 0.f; }
    float mx0 = -1e30f, mx1 = -1e30f, sum0 = 0.f, sum1 = 0.f;
    int cnt = 0;

    for (int m = 0; m < 512; ++m) {
        if (Ms[m] != 0.f) { ++cnt; continue; }
        const float* kr = &Ks[m * 16];
        float s0 = 0.f, s1 = 0.f;
        #pragma unroll
        for (int d = 0; d < 16; ++d) { s0 += q0[d] * kr[d]; s1 += q1[d] * kr[d]; }
        s0 *= NORM_; s1 *= NORM_;
        float w0, w1;
        if (s0 > mx0) {
            float c = __expf(mx0 - s0);
            sum0 *= c;
            #pragma unroll
            for (int d = 0; d < 16; ++d) o0[d] *= c;
            mx0 = s0; w0 = 1.f;
        } else w0 = __expf(s0 - mx0);
        if (s1 > mx1) {
            float c = __expf(mx1 - s1);
            sum1 *= c;
            #pragma unroll
            for (int d = 0; d < 16; ++d) o1[d] *= c;
            mx1 = s1; w1 = 1.f;
        } else w1 = __expf(s1 - mx1);
        sum0 += w0; sum1 += w1;
        const unsigned int* vr = (const unsigned int*)&Vs[m * 16];
        #pragma unroll
        for (int e = 0; e < 8; ++e) {
            unsigned int w = vr[e];
            float vlo = bitsf(w << 16);
            float vhi = bitsf(w & 0xFFFF0000u);
            o0[2 * e]     += w0 * vlo; o0[2 * e + 1] += w0 * vhi;
            o1[2 * e]     += w1 * vlo; o1[2 * e + 1] += w1 * vhi;
        }
    }

    if (cnt > 0) {
        float M0 = mx0 > -30.f ? mx0 : -30.f;
        float M1 = mx1 > -30.f ? mx1 : -30.f;
        if (M0 != mx0) {
            float c = __expf(mx0 - M0);
            sum0 *= c;
            #pragma unroll
            for (int d = 0; d < 16; ++d) o0[d] *= c;
        }
        if (M1 != mx1) {
            float c = __expf(mx1 - M1);
            sum1 *= c;
            #pragma unroll
            for (int d = 0; d < 16; ++d) o1[d] *= c;
        }
        sum0 += (float)cnt * __expf(-30.f - M0);
        sum1 += (float)cnt * __expf(-30.f - M1);
    }

    const float inv0 = 1.f / sum0;
    const float inv1 = 1.f / sum1;
    unsigned short* o0p = Out + ((size_t)(b2 * 512 + t) * 128 + h2 * 16);
    unsigned short* o1p = Out + ((size_t)(b2 * 512 + t + 256) * 128 + h2 * 16);
    #pragma unroll
    for (int d = 0; d < 16; ++d) {
        o0p[d] = f2bf(o0[d] * inv0);
        o1p[d] = f2bf(o1[d] * inv1);
    }
}

// h writeback from f32 master, transport dtype per flag
__global__ __launch_bounds__(256) void write_h(const float* __restrict__ hf,
                                               void* __restrict__ out,
                                               const int* __restrict__ flag)
{
    const size_t i = ((size_t)blockIdx.x * 256 + threadIdx.x) * 4;
    floatx4 v = *(const floatx4*)&hf[i];
    if (*flag) {
        *(floatx4*)((float*)out + i) = v;
    } else {
        unsigned int p0 = (unsigned int)f2bf(v[0]) | ((unsigned int)f2bf(v[1]) << 16);
        unsigned int p1 = (unsigned int)f2bf(v[2]) | ((unsigned int)f2bf(v[3]) << 16);
        unsigned int* o = (unsigned int*)((unsigned short*)out + i);
        o[0] = p0; o[1] = p1;
    }
}

__global__ __launch_bounds__(256) void mean_kernel(const float* __restrict__ hf,
                                                   void* __restrict__ out,
                                                   const int* __restrict__ flag)
{
    const int b = blockIdx.x >> 2;
    const int e = ((blockIdx.x & 3) * 256) + threadIdx.x;
    float s = 0.f;
    for (int n = 0; n < 512; ++n) s += hf[((size_t)(b * 512 + n)) * 1024 + e];
    s *= (1.0f / 512.0f);
    const size_t off = (size_t)16384 * 1024 + b * 1024 + e;
    if (*flag) ((float*)out)[off] = s;
    else       ((unsigned short*)out)[off] = f2bf(s);
}

extern "C" void kernel_launch(void* const* d_in, const int* in_sizes, int n_in,
                              void* d_out, int out_size, void* d_ws, size_t ws_size,
                              hipStream_t stream)
{
    const void* x  = d_in[0];
    const unsigned int* mask = (const unsigned int*)d_in[1];

    // ---- workspace layout ----
    char* ws = (char*)d_ws;
    float* hf = (float*)ws;                     ws += (size_t)16384 * 1024 * 4;   // 64 MB
    unsigned short* hb = (unsigned short*)ws;   ws += (size_t)16384 * 1024 * 2;   // 32 MB
    char* shared_rg = ws;                       ws += (size_t)16384 * 2048 * 2;   // 64 MB (act | qkv+ao)
    unsigned short* act = (unsigned short*)shared_rg;
    unsigned short* q  = (unsigned short*)shared_rg;
    unsigned short* k  = q + (size_t)16384 * 128;
    unsigned short* v  = k + (size_t)16384 * 128;
    unsigned short* ao = v + (size_t)16384 * 128;
    // converted bf16 weights
    unsigned short* cWq = (unsigned short*)ws;  ws += (size_t)393216 * 2;
    unsigned short* cWk = (unsigned short*)ws;  ws += (size_t)393216 * 2;
    unsigned short* cWv = (unsigned short*)ws;  ws += (size_t)393216 * 2;
    unsigned short* cWo = (unsigned short*)ws;  ws += (size_t)393216 * 2;
    unsigned short* cbo = (unsigned short*)ws;  ws += (size_t)3072 * 2;
    unsigned short* cW1 = (unsigned short*)ws;  ws += (size_t)6291456 * 2;
    unsigned short* cb1 = (unsigned short*)ws;  ws += (size_t)6144 * 2;
    unsigned short* cW2 = (unsigned short*)ws;  ws += (size_t)6291456 * 2;
    unsigned short* cb2 = (unsigned short*)ws;  ws += (size_t)3072 * 2;
    float* maskf = (float*)ws;                  ws += (size_t)16384 * 4;
    int* flag = (int*)ws;                       ws += 256;

    detect_dtype<<<1, 256, 0, stream>>>((const unsigned int*)x, flag);

    auto conv = [&](const void* s, unsigned short* d, int n) {
        conv_to_bf16<<<(n / 8 + 255) / 256, 256, 0, stream>>>(s, d, n, flag);
    };
    conv(d_in[2], cWq, 393216);
    conv(d_in[3], cWk, 393216);
    conv(d_in[4], cWv, 393216);
    conv(d_in[5], cWo, 393216);
    conv(d_in[6], cbo, 3072);
    conv(d_in[7], cW1, 6291456);
    conv(d_in[8], cb1, 6144);
    conv(d_in[9], cW2, 6291456);
    conv(d_in[10], cb2, 3072);

    mask_expand<<<64, 256, 0, stream>>>(mask, maskf);
    init_h<<<8192, 256, 0, stream>>>(x, hf, hb, flag);

    for (int l = 0; l < 3; ++l) {
        const unsigned short* wq  = cWq + (size_t)l * 131072;
        const unsigned short* wk  = cWk + (size_t)l * 131072;
        const unsigned short* wv  = cWv + (size_t)l * 131072;
        const unsigned short* wo  = cWo + (size_t)l * 131072;
        const unsigned short* bol = cbo + (size_t)l * 1024;
        const unsigned short* w1  = cW1 + (size_t)l * 2097152;
        const unsigned short* b1l = cb1 + (size_t)l * 2048;
        const unsigned short* w2  = cW2 + (size_t)l * 2097152;
        const unsigned short* b2l = cb2 + (size_t)l * 1024;

        gemm_bt<EPI_NONE><<<dim3(128, 1, 3), 256, 0, stream>>>(
            hb, wq, wk, wv, q, k, v, nullptr, nullptr, nullptr, 128, 1024);
        attn_kernel<<<256, 256, 0, stream>>>(q, k, v, maskf, ao);
        gemm_bt<EPI_BIAS_RES><<<dim3(128, 8, 1), 256, 0, stream>>>(
            ao, wo, wo, wo, nullptr, nullptr, nullptr, bol, hf, hb, 1024, 128);
        gemm_bt<EPI_BIAS_RELU><<<dim3(128, 16, 1), 256, 0, stream>>>(
            hb, w1, w1, w1, act, act, act, b1l, nullptr, nullptr, 2048, 1024);
        gemm_bt<EPI_BIAS_RES><<<dim3(128, 8, 1), 256, 0, stream>>>(
            act, w2, w2, w2, nullptr, nullptr, nullptr, b2l, hf, hb, 1024, 2048);
    }

    write_h<<<16384, 256, 0, stream>>>(hf, d_out, flag);
    mean_kernel<<<128, 256, 0, stream>>>(hf, d_out, flag);
}

// Round 4
// 1361.726 us; speedup vs baseline: 1.0788x; 1.0788x over previous
//
#include <hip/hip_runtime.h>
#include <stdint.h>

// Problem: B=32, N=512, E=1024, H=8, L=3, FF=2048, KD=128, DK=16
// Transport dtype (f32 vs bf16) detected on device; compute bf16 MFMA + f32 master h.

typedef __attribute__((ext_vector_type(8))) short short8;
typedef __attribute__((ext_vector_type(4))) float floatx4;

#define NORM_ 0.08838834764831845f   // 1/sqrt(128)

__device__ __forceinline__ float bf2f(unsigned short u) {
    union { unsigned int i; float f; } x; x.i = ((unsigned int)u) << 16; return x.f;
}
__device__ __forceinline__ unsigned short f2bf(float f) {  // RNE
    union { float f; unsigned int i; } x; x.f = f;
    unsigned int u = x.i;
    u += 0x7FFFu + ((u >> 16) & 1u);
    return (unsigned short)(u >> 16);
}
__device__ __forceinline__ void async_cp16(const void* g, void* l) {
    __builtin_amdgcn_global_load_lds((const __attribute__((address_space(1))) void*)g,
                                     (__attribute__((address_space(3))) void*)l, 16, 0, 0);
}

// ---- transport dtype detection -------------------------------------------
__global__ __launch_bounds__(256) void detect_dtype(const unsigned int* __restrict__ x,
                                                    int* __restrict__ flag)
{
    __shared__ int good, bad;
    if (threadIdx.x == 0) { good = 0; bad = 0; }
    __syncthreads();
    int g = 0, b = 0;
    for (int i = threadIdx.x; i < 4096; i += 256) {
        unsigned int lo = x[i] & 0xFFFFu;
        if (lo != 0u) {
            unsigned int e = (lo >> 7) & 0xFFu;
            if (e >= 90u && e <= 145u) ++g; else ++b;
        }
    }
    atomicAdd(&good, g); atomicAdd(&bad, b);
    __syncthreads();
    if (threadIdx.x == 0) *flag = (bad > good) ? 1 : 0;   // 1 = f32 transport
}

__global__ __launch_bounds__(256) void conv_to_bf16(const void* __restrict__ src,
                                                    unsigned short* __restrict__ dst,
                                                    int n, const int* __restrict__ flag)
{
    const int i = (blockIdx.x * 256 + threadIdx.x) * 8;
    if (i >= n) return;
    if (*flag) {
        const float* s = (const float*)src + i;
        floatx4 a = *(const floatx4*)s;
        floatx4 b = *(const floatx4*)(s + 4);
        short8 o;
        o[0] = (short)f2bf(a[0]); o[1] = (short)f2bf(a[1]);
        o[2] = (short)f2bf(a[2]); o[3] = (short)f2bf(a[3]);
        o[4] = (short)f2bf(b[0]); o[5] = (short)f2bf(b[1]);
        o[6] = (short)f2bf(b[2]); o[7] = (short)f2bf(b[3]);
        *(short8*)(dst + i) = o;
    } else {
        *(short8*)(dst + i) = *(const short8*)((const unsigned short*)src + i);
    }
}

__global__ __launch_bounds__(256) void init_h(const void* __restrict__ x,
                                              float* __restrict__ hf,
                                              unsigned short* __restrict__ hb,
                                              const int* __restrict__ flag)
{
    const size_t i = ((size_t)blockIdx.x * 256 + threadIdx.x) * 8;
    if (*flag) {
        const float* s = (const float*)x + i;
        floatx4 a = *(const floatx4*)s;
        floatx4 b = *(const floatx4*)(s + 4);
        short8 o;
        o[0] = (short)f2bf(a[0]); o[1] = (short)f2bf(a[1]);
        o[2] = (short)f2bf(a[2]); o[3] = (short)f2bf(a[3]);
        o[4] = (short)f2bf(b[0]); o[5] = (short)f2bf(b[1]);
        o[6] = (short)f2bf(b[2]); o[7] = (short)f2bf(b[3]);
        *(short8*)(hb + i) = o;
        *(floatx4*)(hf + i) = a;
        *(floatx4*)(hf + i + 4) = b;
    } else {
        short8 v = *(const short8*)((const unsigned short*)x + i);
        *(short8*)(hb + i) = v;
        #pragma unroll
        for (int e = 0; e < 8; ++e) hf[i + e] = bf2f((unsigned short)v[e]);
    }
}

__global__ __launch_bounds__(256) void mask_expand(const unsigned int* __restrict__ mraw,
                                                   float* __restrict__ maskf)
{
    __shared__ unsigned int r[4];
    if (threadIdx.x < 4) r[threadIdx.x] = 0;
    __syncthreads();
    unsigned int gt1 = 0, badb = 0, badh = 0, lo3f = 0;
    for (int i = threadIdx.x; i < 4096; i += 256) {
        unsigned int w = mraw[i];
        if (w > 1u) gt1 = 1;
        if (w & 0xFEFEFEFEu) badb = 1;
        unsigned int lo = w & 0xFFFFu, hi = w >> 16;
        if ((lo != 0u && lo != 0x3F80u) || (hi != 0u && hi != 0x3F80u)) badh = 1;
        if (lo == 0x3F80u) lo3f = 1;
    }
    if (gt1) atomicOr(&r[0], 1u);
    if (badb) atomicOr(&r[1], 1u);
    if (badh) atomicOr(&r[2], 1u);
    if (lo3f) atomicOr(&r[3], 1u);
    __syncthreads();
    int cls;
    if (!r[0]) cls = 0;
    else if (!r[1]) cls = 1;
    else if (!r[2]) cls = r[3] ? 2 : 3;
    else cls = 0;

    const int gid = blockIdx.x * 256 + threadIdx.x;
    bool m;
    if (cls == 0)      m = ((const int*)mraw)[gid] != 0;
    else if (cls == 1) m = ((const unsigned char*)mraw)[gid] != 0;
    else if (cls == 2) m = ((const unsigned short*)mraw)[gid] != 0;
    else               m = mraw[gid] != 0u;
    maskf[gid] = m ? 1.0f : 0.0f;
}

enum { EPI_NONE = 0, EPI_BIAS_RELU = 1, EPI_BIAS_RES = 2 };

// C[m,n] = sum_k A[m,k]*B[n,k]. 128x128 tile, BK=32, async global_load_lds x16.
template<int EPI>
__global__ __launch_bounds__(256) void gemm_bt(
    const unsigned short* __restrict__ A,
    const unsigned short* __restrict__ Bq,
    const unsigned short* __restrict__ Bk,
    const unsigned short* __restrict__ Bv,
    unsigned short* __restrict__ Cq,
    unsigned short* __restrict__ Ck,
    unsigned short* __restrict__ Cv,
    const unsigned short* __restrict__ bias,
    float* __restrict__ hf,
    unsigned short* __restrict__ hb,
    int N, int K)
{
    __shared__ __align__(16) unsigned short As[128 * 32];
    __shared__ __align__(16) unsigned short Bs[128 * 32];

    const int t = threadIdx.x;
    const int lane = t & 63;
    const int wave = t >> 6;
    const int bm = blockIdx.x;
    const int bn = blockIdx.y;
    const int bz = blockIdx.z;

    const unsigned short* Bmat = (bz == 0) ? Bq : ((bz == 1) ? Bk : Bv);
    unsigned short* C = (bz == 0) ? Cq : ((bz == 1) ? Ck : Cv);

    const int wm = (wave >> 1) * 64;
    const int wn = (wave & 1) * 64;

    const int srow = t >> 2;
    const int scol = (t & 3) * 8;
    const unsigned short* Ag = A + (size_t)(bm * 128 + srow) * K + scol;
    const unsigned short* Bg = Bmat + (size_t)(bn * 128 + srow) * K + scol;
    unsigned short* As0 = &As[srow * 32 + scol];
    unsigned short* As1 = &As[(srow + 64) * 32 + scol];
    unsigned short* Bs0 = &Bs[srow * 32 + scol];
    unsigned short* Bs1 = &Bs[(srow + 64) * 32 + scol];
    const size_t rstep = (size_t)64 * K;

    const int fl = lane & 15;
    const int fk = (lane >> 4) * 8;
    int aoff[4], boff[4];
    #pragma unroll
    for (int i = 0; i < 4; ++i) {
        aoff[i] = (wm + i * 16 + fl) * 32 + fk;
        boff[i] = (wn + i * 16 + fl) * 32 + fk;
    }

    floatx4 acc[4][4];
    #pragma unroll
    for (int i = 0; i < 4; ++i)
        #pragma unroll
        for (int j = 0; j < 4; ++j) {
            acc[i][j][0] = 0.f; acc[i][j][1] = 0.f;
            acc[i][j][2] = 0.f; acc[i][j][3] = 0.f;
        }

    for (int k0 = 0; k0 < K; k0 += 32) {
        __syncthreads();
        async_cp16(Ag + k0, As0);
        async_cp16(Ag + k0 + rstep, As1);
        async_cp16(Bg + k0, Bs0);
        async_cp16(Bg + k0 + rstep, Bs1);
        __syncthreads();

        short8 af[4], bfr[4];
        #pragma unroll
        for (int i = 0; i < 4; ++i) af[i] = *(const short8*)&As[aoff[i]];
        #pragma unroll
        for (int j = 0; j < 4; ++j) bfr[j] = *(const short8*)&Bs[boff[j]];
        #pragma unroll
        for (int i = 0; i < 4; ++i)
            #pragma unroll
            for (int j = 0; j < 4; ++j)
                acc[i][j] = __builtin_amdgcn_mfma_f32_16x16x32_bf16(af[i], bfr[j], acc[i][j], 0, 0, 0);
    }

    const int r0 = (lane >> 4) * 4;
    #pragma unroll
    for (int j = 0; j < 4; ++j) {
        const int gcol = bn * 128 + wn + j * 16 + fl;
        float bval = 0.f;
        if (EPI != EPI_NONE) bval = bf2f(bias[gcol]);
        #pragma unroll
        for (int i = 0; i < 4; ++i) {
            const int growb = bm * 128 + wm + i * 16 + r0;
            #pragma unroll
            for (int r = 0; r < 4; ++r) {
                const size_t idx = (size_t)(growb + r) * N + gcol;
                float v = acc[i][j][r];
                if (EPI == EPI_NONE) {
                    C[idx] = f2bf(v);
                } else if (EPI == EPI_BIAS_RELU) {
                    v += bval;
                    v = v > 0.f ? v : 0.f;
                    C[idx] = f2bf(v);
                } else {
                    float nh = hf[idx] + v + bval;
                    hf[idx] = nh;
                    hb[idx] = f2bf(nh);
                }
            }
        }
    }
}

// MFMA flash attention. blockIdx = pair*4 + qquarter; 128 thr = 2 waves;
// wave handles 64 q-rows (4 qtiles of 16). Keys tiled in slabs of 32.
// S=QK^T via mfma_16x16x32 (D=16 zero-padded); P roundtrips LDS (bf16) to
// A-layout; PV via mfma against V^T (dim-major LDS). Online softmax in
// C-layout with shuffle row-reductions; masked-key class merged at end.
__global__ __launch_bounds__(128) void attn_mfma(
    const unsigned short* __restrict__ Q,
    const unsigned short* __restrict__ Kx,
    const unsigned short* __restrict__ Vx,
    const float* __restrict__ maskf,
    unsigned short* __restrict__ Out)
{
    __shared__ __align__(16) unsigned short Vt[16 * 520];   // V^T dim-major, padded
    __shared__ __align__(16) unsigned short Pb[2][64 * 40]; // per-wave P (q-major, 40-stride)
    __shared__ float Ms[512];
    __shared__ float cnt_s;

    const int t = threadIdx.x;
    const int lane = t & 63;
    const int wave = t >> 6;
    const int p = blockIdx.x >> 2;
    const int qq = blockIdx.x & 3;
    const int b2 = p & 31;
    const int h2 = p >> 5;
    const int fm = lane & 15;       // col within tile (q / key / dim)
    const int g = lane >> 4;        // 0..3

    const unsigned short* Qg = Q + (size_t)p * 8192;
    const unsigned short* Kg = Kx + (size_t)p * 8192;
    const unsigned short* Vg = Vx + (size_t)p * 8192;

    // ---- stage V^T (each thread transposes 4 V rows) ----
    #pragma unroll
    for (int rr = 0; rr < 4; ++rr) {
        const int row = t * 4 + rr;
        short8 v0 = *(const short8*)&Vg[row * 16];
        short8 v1 = *(const short8*)&Vg[row * 16 + 8];
        #pragma unroll
        for (int d = 0; d < 8; ++d) Vt[d * 520 + row] = (unsigned short)v0[d];
        #pragma unroll
        for (int d = 0; d < 8; ++d) Vt[(d + 8) * 520 + row] = (unsigned short)v1[d];
    }
    // ---- mask + masked-count ----
    if (t == 0) cnt_s = 0.f;
    __syncthreads();
    float pc = 0.f;
    #pragma unroll
    for (int it = 0; it < 4; ++it) {
        int i = it * 128 + t;
        float mv = maskf[b2 * 512 + i];
        Ms[i] = mv; pc += mv;
    }
    atomicAdd(&cnt_s, pc);
    __syncthreads();
    const float cnt = cnt_s;

    // ---- Q fragments (4 qtiles), D=16 zero-padded to K=32 ----
    const int qbase = qq * 128 + wave * 64;
    short8 qf[4];
    #pragma unroll
    for (int i = 0; i < 4; ++i) {
        short8 z = {0,0,0,0,0,0,0,0};
        if (g < 2) z = *(const short8*)&Qg[(qbase + i * 16 + fm) * 16 + g * 8];
        qf[i] = z;
    }

    float m_[4][4], l_[4][4];
    floatx4 O[4];
    #pragma unroll
    for (int i = 0; i < 4; ++i) {
        #pragma unroll
        for (int r = 0; r < 4; ++r) { m_[i][r] = -1e30f; l_[i][r] = 0.f; }
        O[i][0] = 0.f; O[i][1] = 0.f; O[i][2] = 0.f; O[i][3] = 0.f;
    }

    unsigned short* Pw = &Pb[wave][0];

    for (int kb = 0; kb < 512; kb += 32) {
        // K fragments for 2 ktiles
        short8 kf0 = {0,0,0,0,0,0,0,0}, kf1 = {0,0,0,0,0,0,0,0};
        if (g < 2) {
            kf0 = *(const short8*)&Kg[(kb + fm) * 16 + g * 8];
            kf1 = *(const short8*)&Kg[(kb + 16 + fm) * 16 + g * 8];
        }
        const float msk0 = Ms[kb + fm];
        const float msk1 = Ms[kb + 16 + fm];

        floatx4 zero4 = {0.f, 0.f, 0.f, 0.f};
        floatx4 s0[4], s1[4];
        #pragma unroll
        for (int i = 0; i < 4; ++i) {
            s0[i] = __builtin_amdgcn_mfma_f32_16x16x32_bf16(qf[i], kf0, zero4, 0, 0, 0);
            s1[i] = __builtin_amdgcn_mfma_f32_16x16x32_bf16(qf[i], kf1, zero4, 0, 0, 0);
        }

        #pragma unroll
        for (int i = 0; i < 4; ++i) {
            #pragma unroll
            for (int r = 0; r < 4; ++r) {
                float a0 = (msk0 != 0.f) ? -1e30f : s0[i][r] * NORM_;
                float a1 = (msk1 != 0.f) ? -1e30f : s1[i][r] * NORM_;
                float mx = fmaxf(a0, a1);
                mx = fmaxf(mx, __shfl_xor(mx, 1));
                mx = fmaxf(mx, __shfl_xor(mx, 2));
                mx = fmaxf(mx, __shfl_xor(mx, 4));
                mx = fmaxf(mx, __shfl_xor(mx, 8));
                const float mo = m_[i][r];
                const float mn = fmaxf(mo, mx);
                const float alpha = __expf(mo - mn);
                float w0 = (msk0 != 0.f) ? 0.f : __expf(a0 - mn);
                float w1 = (msk1 != 0.f) ? 0.f : __expf(a1 - mn);
                float rs = w0 + w1;
                rs += __shfl_xor(rs, 1);
                rs += __shfl_xor(rs, 2);
                rs += __shfl_xor(rs, 4);
                rs += __shfl_xor(rs, 8);
                l_[i][r] = l_[i][r] * alpha + rs;
                m_[i][r] = mn;
                O[i][r] *= alpha;
                const int qloc = i * 16 + g * 4 + r;
                Pw[qloc * 40 + fm] = f2bf(w0);
                Pw[qloc * 40 + 16 + fm] = f2bf(w1);
            }
        }
        // drain LDS writes before same-wave cross-lane reads (DS is in-order per wave)
        asm volatile("s_waitcnt lgkmcnt(0)" ::: "memory");

        short8 vtf = *(const short8*)&Vt[fm * 520 + kb + g * 8];
        #pragma unroll
        for (int i = 0; i < 4; ++i) {
            short8 pf = *(const short8*)&Pw[(i * 16 + fm) * 40 + g * 8];
            O[i] = __builtin_amdgcn_mfma_f32_16x16x32_bf16(pf, vtf, O[i], 0, 0, 0);
        }
    }

    // ---- finalize: merge masked class (cnt keys at -30), normalize, store ----
    #pragma unroll
    for (int i = 0; i < 4; ++i) {
        #pragma unroll
        for (int r = 0; r < 4; ++r) {
            const float M = fmaxf(m_[i][r], -30.f);
            const float adj = __expf(m_[i][r] - M);
            const float lf = l_[i][r] * adj + cnt * __expf(-30.f - M);
            const float oval = O[i][r] * adj / lf;
            const int n = qbase + i * 16 + g * 4 + r;
            Out[((size_t)(b2 * 512 + n)) * 128 + h2 * 16 + fm] = f2bf(oval);
        }
    }
}

__global__ __launch_bounds__(256) void write_h(const float* __restrict__ hf,
                                               void* __restrict__ out,
                                               const int* __restrict__ flag)
{
    const size_t i = ((size_t)blockIdx.x * 256 + threadIdx.x) * 4;
    floatx4 v = *(const floatx4*)&hf[i];
    if (*flag) {
        *(floatx4*)((float*)out + i) = v;
    } else {
        unsigned int p0 = (unsigned int)f2bf(v[0]) | ((unsigned int)f2bf(v[1]) << 16);
        unsigned int p1 = (unsigned int)f2bf(v[2]) | ((unsigned int)f2bf(v[3]) << 16);
        unsigned int* o = (unsigned int*)((unsigned short*)out + i);
        o[0] = p0; o[1] = p1;
    }
}

__global__ __launch_bounds__(256) void mean_kernel(const float* __restrict__ hf,
                                                   void* __restrict__ out,
                                                   const int* __restrict__ flag)
{
    const int b = blockIdx.x >> 2;
    const int e = ((blockIdx.x & 3) * 256) + threadIdx.x;
    float s = 0.f;
    for (int n = 0; n < 512; ++n) s += hf[((size_t)(b * 512 + n)) * 1024 + e];
    s *= (1.0f / 512.0f);
    const size_t off = (size_t)16384 * 1024 + b * 1024 + e;
    if (*flag) ((float*)out)[off] = s;
    else       ((unsigned short*)out)[off] = f2bf(s);
}

extern "C" void kernel_launch(void* const* d_in, const int* in_sizes, int n_in,
                              void* d_out, int out_size, void* d_ws, size_t ws_size,
                              hipStream_t stream)
{
    const void* x  = d_in[0];
    const unsigned int* mask = (const unsigned int*)d_in[1];

    char* ws = (char*)d_ws;
    float* hf = (float*)ws;                     ws += (size_t)16384 * 1024 * 4;   // 64 MB
    unsigned short* hb = (unsigned short*)ws;   ws += (size_t)16384 * 1024 * 2;   // 32 MB
    char* shared_rg = ws;                       ws += (size_t)16384 * 2048 * 2;   // 64 MB
    unsigned short* act = (unsigned short*)shared_rg;
    unsigned short* q  = (unsigned short*)shared_rg;
    unsigned short* k  = q + (size_t)16384 * 128;
    unsigned short* v  = k + (size_t)16384 * 128;
    unsigned short* ao = v + (size_t)16384 * 128;
    unsigned short* cWq = (unsigned short*)ws;  ws += (size_t)393216 * 2;
    unsigned short* cWk = (unsigned short*)ws;  ws += (size_t)393216 * 2;
    unsigned short* cWv = (unsigned short*)ws;  ws += (size_t)393216 * 2;
    unsigned short* cWo = (unsigned short*)ws;  ws += (size_t)393216 * 2;
    unsigned short* cbo = (unsigned short*)ws;  ws += (size_t)3072 * 2;
    unsigned short* cW1 = (unsigned short*)ws;  ws += (size_t)6291456 * 2;
    unsigned short* cb1 = (unsigned short*)ws;  ws += (size_t)6144 * 2;
    unsigned short* cW2 = (unsigned short*)ws;  ws += (size_t)6291456 * 2;
    unsigned short* cb2 = (unsigned short*)ws;  ws += (size_t)3072 * 2;
    float* maskf = (float*)ws;                  ws += (size_t)16384 * 4;
    int* flag = (int*)ws;                       ws += 256;

    detect_dtype<<<1, 256, 0, stream>>>((const unsigned int*)x, flag);

    auto conv = [&](const void* s, unsigned short* d, int n) {
        conv_to_bf16<<<(n / 8 + 255) / 256, 256, 0, stream>>>(s, d, n, flag);
    };
    conv(d_in[2], cWq, 393216);
    conv(d_in[3], cWk, 393216);
    conv(d_in[4], cWv, 393216);
    conv(d_in[5], cWo, 393216);
    conv(d_in[6], cbo, 3072);
    conv(d_in[7], cW1, 6291456);
    conv(d_in[8], cb1, 6144);
    conv(d_in[9], cW2, 6291456);
    conv(d_in[10], cb2, 3072);

    mask_expand<<<64, 256, 0, stream>>>(mask, maskf);
    init_h<<<8192, 256, 0, stream>>>(x, hf, hb, flag);

    for (int l = 0; l < 3; ++l) {
        const unsigned short* wq  = cWq + (size_t)l * 131072;
        const unsigned short* wk  = cWk + (size_t)l * 131072;
        const unsigned short* wv  = cWv + (size_t)l * 131072;
        const unsigned short* wo  = cWo + (size_t)l * 131072;
        const unsigned short* bol = cbo + (size_t)l * 1024;
        const unsigned short* w1  = cW1 + (size_t)l * 2097152;
        const unsigned short* b1l = cb1 + (size_t)l * 2048;
        const unsigned short* w2  = cW2 + (size_t)l * 2097152;
        const unsigned short* b2l = cb2 + (size_t)l * 1024;

        gemm_bt<EPI_NONE><<<dim3(128, 1, 3), 256, 0, stream>>>(
            hb, wq, wk, wv, q, k, v, nullptr, nullptr, nullptr, 128, 1024);
        attn_mfma<<<1024, 128, 0, stream>>>(q, k, v, maskf, ao);
        gemm_bt<EPI_BIAS_RES><<<dim3(128, 8, 1), 256, 0, stream>>>(
            ao, wo, wo, wo, nullptr, nullptr, nullptr, bol, hf, hb, 1024, 128);
        gemm_bt<EPI_BIAS_RELU><<<dim3(128, 16, 1), 256, 0, stream>>>(
            hb, w1, w1, w1, act, act, act, b1l, nullptr, nullptr, 2048, 1024);
        gemm_bt<EPI_BIAS_RES><<<dim3(128, 8, 1), 256, 0, stream>>>(
            act, w2, w2, w2, nullptr, nullptr, nullptr, b2l, hf, hb, 1024, 2048);
    }

    write_h<<<16384, 256, 0, stream>>>(hf, d_out, flag);
    mean_kernel<<<128, 256, 0, stream>>>(hf, d_out, flag);
}